// Round 1
// baseline (1640.174 us; speedup 1.0000x reference)
//
#include <hip/hip_runtime.h>

// ---------------------------------------------------------------------------
// Net_75282186764473: two-stage PAT ODE net, forward == experiment dynamics.
//   pat(z) = zm + stop_grad(ze - zm)  ==> forward value is exactly ze.
// Stage dynamics (explicit Euler, 5 steps, dt=0.1):
//   sq = sin(1.1*q);  dp[j] = e[j] + sum_i sq[i]*M[i][j]
//   with M = c2q(W) + Qn - I   (the "-sq" term folded into M's diagonal)
//   q += dt*p_old;  p += dt*dp(q_old)
// Stage1: N=196, init q=x, p=0. Stage2: N=206, q=[q1;0*10], p=0.
// Output: fac * q2[:, 196:206]   (65536 x 10, fp32)
// ---------------------------------------------------------------------------

#define BT 32            // batch rows per block
#define NTH 256          // threads per block (thread j owns column j)
#define SQ_STRIDE 36     // floats per LDS row: 144B, 16B-aligned, non-pow2 pad

__device__ __constant__ const float kDT = 0.1f;    // 0.5 / 5
__device__ __constant__ const float kETA = 1.1f;   // 1 + ETA

// Build M[i][j] = c2q(C)[i][j] + Qn[i][j] - (i==j), column-parallel.
// c2q: Q = 0.5*(C+C^T); Q[j][j] = -sum_i 0.5*(C[i][j]+C[j][i]) (incl. diag).
__global__ void prep_M(const float* __restrict__ C, const float* __restrict__ Qn,
                       float* __restrict__ M, int N) {
    const int j = blockIdx.x;      // one wave per column
    const int t = threadIdx.x;     // 64 threads
    if (j >= N) return;
    float s = 0.f;
    for (int i = t; i < N; i += 64)
        s += 0.5f * (C[i * N + j] + C[j * N + i]);
    // butterfly reduce across the wave: every lane ends with the column sum
    #pragma unroll
    for (int off = 32; off > 0; off >>= 1)
        s += __shfl_xor(s, off, 64);
    for (int i = t; i < N; i += 64) {
        float v;
        if (i == j)
            v = -s - 1.0f;                              // c2q diag, -I fold
        else
            v = 0.5f * (C[i * N + j] + C[j * N + i]);
        M[i * N + j] = v + Qn[i * N + j];
    }
}

template <int N>
__device__ __forceinline__ void run_stage(float (&q)[BT], float (&p)[BT],
                                          const float* __restrict__ M,
                                          const float* __restrict__ evec,
                                          float* __restrict__ sq, int j) {
    const float ej = (j < N) ? evec[j] : 0.f;
    for (int s = 0; s < 5; ++s) {
        // phase 1: sq tile (LDS layout [j][b], padded stride)
        if (j < N) {
            #pragma unroll
            for (int b = 0; b < BT; b += 4) {
                float4 v;
                v.x = __sinf(kETA * q[b + 0]);
                v.y = __sinf(kETA * q[b + 1]);
                v.z = __sinf(kETA * q[b + 2]);
                v.w = __sinf(kETA * q[b + 3]);
                *(float4*)(&sq[j * SQ_STRIDE + b]) = v;
            }
        }
        __syncthreads();
        // phase 2: dp = sq @ M column j; then Euler update
        if (j < N) {
            float dp[BT];
            #pragma unroll
            for (int b = 0; b < BT; ++b) dp[b] = 0.f;
            const float* Mj = M + j;
            #pragma unroll 2
            for (int i = 0; i < N; ++i) {
                const float m = Mj[(size_t)i * N];          // coalesced over j
                const float4* sp = (const float4*)(sq + i * SQ_STRIDE);
                #pragma unroll
                for (int bb = 0; bb < BT / 4; ++bb) {
                    float4 sv = sp[bb];                     // broadcast read
                    dp[4 * bb + 0] = fmaf(sv.x, m, dp[4 * bb + 0]);
                    dp[4 * bb + 1] = fmaf(sv.y, m, dp[4 * bb + 1]);
                    dp[4 * bb + 2] = fmaf(sv.z, m, dp[4 * bb + 2]);
                    dp[4 * bb + 3] = fmaf(sv.w, m, dp[4 * bb + 3]);
                }
            }
            #pragma unroll
            for (int b = 0; b < BT; ++b) {
                q[b] += kDT * p[b];                 // uses old p
                p[b] += kDT * (ej + dp[b]);         // dp from old q
            }
        }
        __syncthreads();
    }
}

__global__ __launch_bounds__(NTH) void pat_fused(
    const float* __restrict__ x,
    const float* __restrict__ e1, const float* __restrict__ e2,
    const float* __restrict__ M1, const float* __restrict__ M2,
    const float* __restrict__ fac,
    float* __restrict__ out) {
    __shared__ float sq[206 * SQ_STRIDE];   // 29,664 B
    const int j = threadIdx.x;
    const long b0 = (long)blockIdx.x * BT;

    float q[BT], p[BT];
    // stage-1 init: q = x (cols 196..255 stay 0 and are inert in stage 1)
    if (j < 196) {
        #pragma unroll 4
        for (int b = 0; b < BT; ++b) q[b] = x[(b0 + b) * 196 + j];
    } else {
        #pragma unroll
        for (int b = 0; b < BT; ++b) q[b] = 0.f;
    }
    #pragma unroll
    for (int b = 0; b < BT; ++b) p[b] = 0.f;

    run_stage<196>(q, p, M1, e1, sq, j);

    // transition: keep q (class nodes j>=196 still hold 0), reset p
    #pragma unroll
    for (int b = 0; b < BT; ++b) p[b] = 0.f;

    run_stage<206>(q, p, M2, e2, sq, j);

    // epilogue: out[b, j-196] = fac * q2
    if (j >= 196 && j < 206) {
        const float f = fac[0];
        #pragma unroll
        for (int b = 0; b < BT; ++b)
            out[(b0 + b) * 10 + (j - 196)] = f * q[b];
    }
}

extern "C" void kernel_launch(void* const* d_in, const int* in_sizes, int n_in,
                              void* d_out, int out_size, void* d_ws, size_t ws_size,
                              hipStream_t stream) {
    const float* x   = (const float*)d_in[0];
    const float* w1  = (const float*)d_in[1];
    const float* b1  = (const float*)d_in[2];
    const float* w2  = (const float*)d_in[3];
    const float* b2  = (const float*)d_in[4];
    const float* fac = (const float*)d_in[5];
    const float* qn1 = (const float*)d_in[6];
    const float* qn2 = (const float*)d_in[7];
    float* out = (float*)d_out;

    float* M1 = (float*)d_ws;              // 196*196 floats
    float* M2 = M1 + 196 * 196;            // 206*206 floats (total ~324 KB)

    prep_M<<<196, 64, 0, stream>>>(w1, qn1, M1, 196);
    prep_M<<<206, 64, 0, stream>>>(w2, qn2, M2, 206);

    const int B = in_sizes[0] / 196;       // 65536
    pat_fused<<<B / BT, NTH, 0, stream>>>(x, b1, b2, M1, M2, fac, out);
}